// Round 2
// baseline (829.375 us; speedup 1.0000x reference)
//
#include <hip/hip_runtime.h>
#include <cstddef>

#define A_ATOMS 96
#define BATCH   128
#define NNODES  12288   // B*A
#define NROWS3  36864   // N*3

__device__ __forceinline__ float silu_f(float x) {
    // x * rcp(1+e^-x): v_exp + v_rcp, no precise-div sequence
    float e = __expf(-x);
    return x * __builtin_amdgcn_rcpf(1.0f + e);
}

// ---------- gemm96: vmix = vrep @ mixW1, fused with ||vV|| + xin build ------
// 96 rows/block (= 32 whole nodes), 256 threads, 6x8 micro-tile, K=128.
__global__ __launch_bounds__(256)
void gemm96_k(const float* __restrict__ A, const float* __restrict__ W,
              const float* __restrict__ srep,
              float* __restrict__ vmix, float* __restrict__ xin) {
    __shared__ float smem[96 * 128];           // aliased: As/Bs then Cs
    float* As = smem;                          // [8][96]  (k-major)
    float* Bs = smem + 768;                    // [8][128]
    const int t  = threadIdx.x;
    const int tx = t & 15;                     // cols tx*8..+7
    const int ty = t >> 4;                     // rows ty*6..+5
    const int row0 = blockIdx.x * 96;

    float acc[6][8];
#pragma unroll
    for (int i = 0; i < 6; i++)
#pragma unroll
        for (int j = 0; j < 8; j++) acc[i][j] = 0.0f;

    for (int kc = 0; kc < 128; kc += 8) {
        if (t < 192) {                         // A tile: 96 rows x 8 k
            const int m  = t >> 1;
            const int k4 = (t & 1) * 4;
            float4 av = *(const float4*)(A + (size_t)(row0 + m) * 128 + kc + k4);
            As[(k4 + 0) * 96 + m] = av.x; As[(k4 + 1) * 96 + m] = av.y;
            As[(k4 + 2) * 96 + m] = av.z; As[(k4 + 3) * 96 + m] = av.w;
        }
        {                                      // B tile: 8 k x 128 cols
            const int kb = t >> 5;
            const int n4 = (t & 31) * 4;
            *(float4*)&Bs[kb * 128 + n4] = *(const float4*)(W + (size_t)(kc + kb) * 128 + n4);
        }
        __syncthreads();
#pragma unroll
        for (int k = 0; k < 8; k++) {
            float bf[8], af[6];
            *(float4*)&bf[0] = *(const float4*)&Bs[k * 128 + tx * 8];
            *(float4*)&bf[4] = *(const float4*)&Bs[k * 128 + tx * 8 + 4];
            *(float2*)&af[0] = *(const float2*)&As[k * 96 + ty * 6];
            *(float2*)&af[2] = *(const float2*)&As[k * 96 + ty * 6 + 2];
            *(float2*)&af[4] = *(const float2*)&As[k * 96 + ty * 6 + 4];
#pragma unroll
            for (int i = 0; i < 6; i++)
#pragma unroll
                for (int j = 0; j < 8; j++) acc[i][j] += af[i] * bf[j];
        }
        __syncthreads();
    }

    // write vmix (global) and Cs (LDS, aliasing As/Bs — safe after last sync)
    float* Cs = smem;                          // [96][128]
#pragma unroll
    for (int i = 0; i < 6; i++) {
        const int m = ty * 6 + i;
        float* gp = vmix + (size_t)(row0 + m) * 128 + tx * 8;
        *(float4*)gp       = *(float4*)&acc[i][0];
        *(float4*)(gp + 4) = *(float4*)&acc[i][4];
        *(float4*)&Cs[m * 128 + tx * 8]     = *(float4*)&acc[i][0];
        *(float4*)&Cs[m * 128 + tx * 8 + 4] = *(float4*)&acc[i][4];
    }
    __syncthreads();

    const int node0 = row0 / 3;                // 32 nodes per block
    // xin[:,0:128] = srep   (32*128 floats = 1024 float4)
#pragma unroll
    for (int it = 0; it < 4; it++) {
        const int idx = it * 256 + t;          // float4 index
        const int a   = idx >> 5;
        const int c4  = (idx & 31) * 4;
        *(float4*)(xin + (size_t)(node0 + a) * 192 + c4) =
            *(const float4*)(srep + (size_t)(node0 + a) * 128 + c4);
    }
    // xin[:,128:192] = ||vV||  (32 nodes x 64 cols)
#pragma unroll
    for (int it = 0; it < 8; it++) {
        const int idx = it * 256 + t;
        const int a   = idx >> 6;
        const int c   = idx & 63;
        const float v0 = Cs[(3 * a + 0) * 128 + c];
        const float v1 = Cs[(3 * a + 1) * 128 + c];
        const float v2 = Cs[(3 * a + 2) * 128 + c];
        xin[(size_t)(node0 + a) * 192 + 128 + c] = sqrtf(v0 * v0 + v1 * v1 + v2 * v2);
    }
}

// ---------- gemmN: C = act(A@W + bias), 64-row x 64-col blocks --------------
// 256 threads, 4x4 micro-tile. Grid: (M/64, 128/64).
template<int ACT>
__global__ __launch_bounds__(256)
void gemmN_k(const float* __restrict__ A, const float* __restrict__ W,
             const float* __restrict__ bias, float* __restrict__ C,
             int M, int K) {
    __shared__ float As[8][64];
    __shared__ float Bs[8][64];
    const int t  = threadIdx.x;
    const int tx = t & 15;                     // cols tx*4..+3
    const int ty = t >> 4;                     // rows ty*4..+3
    const int row0 = blockIdx.x * 64;
    const int col0 = blockIdx.y * 64;

    float acc[4][4];
#pragma unroll
    for (int i = 0; i < 4; i++)
#pragma unroll
        for (int j = 0; j < 4; j++) acc[i][j] = 0.0f;

    for (int kc = 0; kc < K; kc += 8) {
        {
            const int m  = t >> 2;
            const int k2 = (t & 3) * 2;
            float2 av = *(const float2*)(A + (size_t)(row0 + m) * K + kc + k2);
            As[k2 + 0][m] = av.x; As[k2 + 1][m] = av.y;
        }
        {
            const int kb = t >> 5;
            const int n2 = (t & 31) * 2;
            *(float2*)&Bs[kb][n2] = *(const float2*)(W + (size_t)(kc + kb) * 128 + col0 + n2);
        }
        __syncthreads();
#pragma unroll
        for (int k = 0; k < 8; k++) {
            float af[4], bf[4];
            *(float4*)&af[0] = *(const float4*)&As[k][ty * 4];
            *(float4*)&bf[0] = *(const float4*)&Bs[k][tx * 4];
#pragma unroll
            for (int i = 0; i < 4; i++)
#pragma unroll
                for (int j = 0; j < 4; j++) acc[i][j] += af[i] * bf[j];
        }
        __syncthreads();
    }
#pragma unroll
    for (int i = 0; i < 4; i++) {
        const int row = row0 + ty * 4 + i;
        float v[4];
#pragma unroll
        for (int j = 0; j < 4; j++) {
            float x = acc[i][j] + bias[col0 + tx * 4 + j];
            if (ACT == 1) x = silu_f(x);
            v[j] = x;
        }
        *(float4*)(C + (size_t)row * 128 + col0 + tx * 4) = *(float4*)&v[0];
    }
}

// ---------------- glue2: per-node block-1 epilogue + full block-2 -----------
#define RED64(v) { v += __shfl_xor(v, 1); v += __shfl_xor(v, 2); v += __shfl_xor(v, 4); \
                   v += __shfl_xor(v, 8); v += __shfl_xor(v, 16); v += __shfl_xor(v, 32); }

__global__ __launch_bounds__(256)
void glue2_k(const float* __restrict__ x1, const float* __restrict__ vmix,
             const float* __restrict__ mixW2,
             const float* __restrict__ W1, const float* __restrict__ b1,
             const float* __restrict__ W2, const float* __restrict__ b2,
             float* __restrict__ l0v, float* __restrict__ l1v) {
    __shared__ float s1s[4][64];
    const int t = threadIdx.x;
    const int w = t >> 6, lane = t & 63;
    const int n = blockIdx.x * 4 + w;

    const float xa = x1[(size_t)n * 128 + lane];        // pre-silu s_out
    const float xb = x1[(size_t)n * 128 + 64 + lane];   // gate
    const float s1 = silu_f(xa);
    const float v1_0 = xb * vmix[((size_t)(3 * n + 0)) * 128 + 64 + lane];
    const float v1_1 = xb * vmix[((size_t)(3 * n + 1)) * 128 + 64 + lane];
    const float v1_2 = xb * vmix[((size_t)(3 * n + 2)) * 128 + 64 + lane];

    const float w0 = mixW2[lane * 2 + 0], w1 = mixW2[lane * 2 + 1];
    float p0 = v1_0 * w0, p1 = v1_0 * w1;
    float p2 = v1_1 * w0, p3 = v1_1 * w1;
    float p4 = v1_2 * w0, p5 = v1_2 * w1;
    RED64(p0); RED64(p1); RED64(p2); RED64(p3); RED64(p4); RED64(p5);
    const float vn2 = sqrtf(p0 * p0 + p2 * p2 + p4 * p4);

    s1s[w][lane] = s1;
    __syncthreads();

    float acc = b1[lane] + vn2 * W1[64 * 64 + lane];
#pragma unroll 8
    for (int i2 = 0; i2 < 64; i2++) acc += s1s[w][i2] * W1[i2 * 64 + lane];
    const float h2 = silu_f(acc);

    float q0 = h2 * W2[lane * 2 + 0];
    float q1 = h2 * W2[lane * 2 + 1];
    RED64(q0); RED64(q1);

    if (lane == 0) {
        const float s_out = q0 + b2[0];   // sact=False: no silu
        const float gate  = q1 + b2[1];
        l0v[n] = s_out;
        l1v[(size_t)n * 3 + 0] = gate * p1;
        l1v[(size_t)n * 3 + 1] = gate * p3;
        l1v[(size_t)n * 3 + 2] = gate * p5;
    }
}

// ---------------- pair kernel: all four small MLPs + scattered write --------
__global__ __launch_bounds__(192)
void pair_k(const float* __restrict__ l0v, const float* __restrict__ l1v,
            const float* __restrict__ pos,
            const float* __restrict__ vvW1, const float* __restrict__ vvb1,
            const float* __restrict__ vvW2, const float* __restrict__ vvb2,
            const float* __restrict__ vrW1, const float* __restrict__ vrb1,
            const float* __restrict__ vrW2, const float* __restrict__ vrb2,
            const float* __restrict__ sW1,  const float* __restrict__ sb1,
            const float* __restrict__ sW2,  const float* __restrict__ sb2,
            const float* __restrict__ hW1,  const float* __restrict__ hb1,
            const float* __restrict__ hW2,  const float* __restrict__ hb2,
            float* __restrict__ out) {
    const int t = threadIdx.x;
    const int b = blockIdx.y;
    const int i = blockIdx.x * 2 + t / 96;
    const int j = t % 96;
    const int ni = b * A_ATOMS + i;
    const int nj = b * A_ATOMS + j;

    const float li0 = l1v[ni * 3 + 0], li1 = l1v[ni * 3 + 1], li2 = l1v[ni * 3 + 2];
    const float lj0 = l1v[nj * 3 + 0], lj1 = l1v[nj * 3 + 1], lj2 = l1v[nj * 3 + 2];
    const float pj0 = pos[nj * 3 + 0], pj1 = pos[nj * 3 + 1], pj2 = pos[nj * 3 + 2];
    const float s0i = l0v[ni], s0j = l0v[nj];

    float vin[9] = { li0*lj0, li0*lj1, li0*lj2,
                     li1*lj0, li1*lj1, li1*lj2,
                     li2*lj0, li2*lj1, li2*lj2 };
    float rin[9] = { li0*pj0, li0*pj1, li0*pj2,
                     li1*pj0, li1*pj1, li1*pj2,
                     li2*pj0, li2*pj1, li2*pj2 };

    float t9[9];
#pragma unroll
    for (int l = 0; l < 9; l++) t9[l] = vvb2[l] + vrb2[l] + sb2[l];

#pragma unroll
    for (int h = 0; h < 30; h++) {
        float av = vvb1[h], ar = vrb1[h];
#pragma unroll
        for (int m = 0; m < 9; m++) {
            av += vin[m] * vvW1[m * 30 + h];
            ar += rin[m] * vrW1[m * 30 + h];
        }
        float as = sb1[h] + s0i * sW1[h] + s0j * sW1[30 + h];
        av = silu_f(av); ar = silu_f(ar); as = silu_f(as);
#pragma unroll
        for (int l = 0; l < 9; l++)
            t9[l] += av * vvW2[h * 9 + l] + ar * vrW2[h * 9 + l] + as * sW2[h * 9 + l];
    }

    float o9[9];
#pragma unroll
    for (int l = 0; l < 9; l++) o9[l] = hb2[l];
#pragma unroll
    for (int h = 0; h < 30; h++) {
        float a = hb1[h];
#pragma unroll
        for (int m = 0; m < 9; m++) a += t9[m] * hW1[m * 30 + h];
        a = silu_f(a);
#pragma unroll
        for (int l = 0; l < 9; l++) o9[l] += a * hW2[h * 9 + l];
    }

    // out[((b*A+i)*3+k)*288 + j*3 + l] = o9[3k+l]
    const size_t rb = (size_t)(b * A_ATOMS + i);
#pragma unroll
    for (int k = 0; k < 3; k++) {
        const size_t off = (rb * 3 + k) * 288 + (size_t)j * 3;
        out[off + 0] = o9[3 * k + 0];
        out[off + 1] = o9[3 * k + 1];
        out[off + 2] = o9[3 * k + 2];
    }
}

extern "C" void kernel_launch(void* const* d_in, const int* in_sizes, int n_in,
                              void* d_out, int out_size, void* d_ws, size_t ws_size,
                              hipStream_t stream) {
    const float* pos   = (const float*)d_in[0];
    const float* srep  = (const float*)d_in[1];
    const float* vrep  = (const float*)d_in[2];
    const float* mixW1 = (const float*)d_in[3];
    const float* sc1W1 = (const float*)d_in[4];
    const float* sc1b1 = (const float*)d_in[5];
    const float* sc1W2 = (const float*)d_in[6];
    const float* sc1b2 = (const float*)d_in[7];
    const float* mixW2 = (const float*)d_in[8];
    const float* sc2W1 = (const float*)d_in[9];
    const float* sc2b1 = (const float*)d_in[10];
    const float* sc2W2 = (const float*)d_in[11];
    const float* sc2b2 = (const float*)d_in[12];
    const float* vvW1  = (const float*)d_in[13];
    const float* vvb1  = (const float*)d_in[14];
    const float* vvW2  = (const float*)d_in[15];
    const float* vvb2  = (const float*)d_in[16];
    const float* vrW1  = (const float*)d_in[17];
    const float* vrb1  = (const float*)d_in[18];
    const float* vrW2  = (const float*)d_in[19];
    const float* vrb2  = (const float*)d_in[20];
    const float* sW1   = (const float*)d_in[21];
    const float* sb1   = (const float*)d_in[22];
    const float* sW2   = (const float*)d_in[23];
    const float* sb2   = (const float*)d_in[24];
    const float* hW1   = (const float*)d_in[25];
    const float* hb1   = (const float*)d_in[26];
    const float* hW2   = (const float*)d_in[27];
    const float* hb2   = (const float*)d_in[28];

    float* ws   = (float*)d_ws;
    float* vmix = ws;                       // 36864*128 = 4,718,592
    float* xin  = vmix + 4718592;           // 12288*192 = 2,359,296
    float* hmid = xin  + 2359296;           // 12288*128 = 1,572,864
    float* x1   = hmid + 1572864;           // 12288*128 = 1,572,864
    float* l0v  = x1   + 1572864;           // 12288
    float* l1v  = l0v  + 12288;             // 36864
    float* outf = (float*)d_out;

    // 1. vmix = vector_rep @ mix_W1, fused norm -> xin
    gemm96_k<<<NROWS3 / 96, 256, 0, stream>>>(vrep, mixW1, srep, vmix, xin);
    // 2. hmid = silu(xin @ sc1_W1 + b1)
    gemmN_k<1><<<dim3(NNODES / 64, 2), 256, 0, stream>>>(xin, sc1W1, sc1b1, hmid, NNODES, 192);
    // 3. x1 = hmid @ sc1_W2 + b2
    gemmN_k<0><<<dim3(NNODES / 64, 2), 256, 0, stream>>>(hmid, sc1W2, sc1b2, x1, NNODES, 128);
    // 4. per-node epilogue + block 2 -> l0, l1
    glue2_k<<<NNODES / 4, 256, 0, stream>>>(x1, vmix, mixW2, sc2W1, sc2b1, sc2W2, sc2b2,
                                            l0v, l1v);
    // 5. pair stage
    pair_k<<<dim3(A_ATOMS / 2, BATCH), 192, 0, stream>>>(
        l0v, l1v, pos,
        vvW1, vvb1, vvW2, vvb2,
        vrW1, vrb1, vrW2, vrb2,
        sW1, sb1, sW2, sb2,
        hW1, hb1, hW2, hb2,
        outf);
}

// Round 3
// 305.976 us; speedup vs baseline: 2.7106x; 2.7106x over previous
//
#include <hip/hip_runtime.h>
#include <cstddef>

#define A_ATOMS 96
#define BATCH   128
#define NNODES  12288   // B*A
#define NROWS3  36864   // N*3

__device__ __forceinline__ float silu_f(float x) {
    // x * rcp(1+e^-x): v_exp + v_rcp, no precise-div sequence
    float e = __expf(-x);
    return x * __builtin_amdgcn_rcpf(1.0f + e);
}

// ---------- gemm96: vmix = vrep @ mixW1, fused with ||vV|| + xin build ------
// 96 rows/block (= 32 whole nodes), 256 threads, 6x8 micro-tile, K=128.
__global__ __launch_bounds__(256)
void gemm96_k(const float* __restrict__ A, const float* __restrict__ W,
              const float* __restrict__ srep,
              float* __restrict__ vmix, float* __restrict__ xin) {
    __shared__ float smem[96 * 128];           // aliased: As/Bs then Cs
    float* As = smem;                          // [8][96]  (k-major)
    float* Bs = smem + 768;                    // [8][128]
    const int t  = threadIdx.x;
    const int tx = t & 15;                     // cols tx*8..+7
    const int ty = t >> 4;                     // rows ty*6..+5
    const int row0 = blockIdx.x * 96;

    float acc[6][8];
#pragma unroll
    for (int i = 0; i < 6; i++)
#pragma unroll
        for (int j = 0; j < 8; j++) acc[i][j] = 0.0f;

    for (int kc = 0; kc < 128; kc += 8) {
        if (t < 192) {                         // A tile: 96 rows x 8 k
            const int m  = t >> 1;
            const int k4 = (t & 1) * 4;
            float4 av = *(const float4*)(A + (size_t)(row0 + m) * 128 + kc + k4);
            As[(k4 + 0) * 96 + m] = av.x; As[(k4 + 1) * 96 + m] = av.y;
            As[(k4 + 2) * 96 + m] = av.z; As[(k4 + 3) * 96 + m] = av.w;
        }
        {                                      // B tile: 8 k x 128 cols
            const int kb = t >> 5;
            const int n4 = (t & 31) * 4;
            *(float4*)&Bs[kb * 128 + n4] = *(const float4*)(W + (size_t)(kc + kb) * 128 + n4);
        }
        __syncthreads();
#pragma unroll
        for (int k = 0; k < 8; k++) {
            float bf[8], af[6];
            *(float4*)&bf[0] = *(const float4*)&Bs[k * 128 + tx * 8];
            *(float4*)&bf[4] = *(const float4*)&Bs[k * 128 + tx * 8 + 4];
            *(float2*)&af[0] = *(const float2*)&As[k * 96 + ty * 6];
            *(float2*)&af[2] = *(const float2*)&As[k * 96 + ty * 6 + 2];
            *(float2*)&af[4] = *(const float2*)&As[k * 96 + ty * 6 + 4];
#pragma unroll
            for (int i = 0; i < 6; i++)
#pragma unroll
                for (int j = 0; j < 8; j++) acc[i][j] += af[i] * bf[j];
        }
        __syncthreads();
    }

    // write vmix (global) and Cs (LDS, aliasing As/Bs — safe after last sync)
    float* Cs = smem;                          // [96][128]
#pragma unroll
    for (int i = 0; i < 6; i++) {
        const int m = ty * 6 + i;
        float* gp = vmix + (size_t)(row0 + m) * 128 + tx * 8;
        *(float4*)gp       = *(float4*)&acc[i][0];
        *(float4*)(gp + 4) = *(float4*)&acc[i][4];
        *(float4*)&Cs[m * 128 + tx * 8]     = *(float4*)&acc[i][0];
        *(float4*)&Cs[m * 128 + tx * 8 + 4] = *(float4*)&acc[i][4];
    }
    __syncthreads();

    const int node0 = row0 / 3;                // 32 nodes per block
    // xin[:,0:128] = srep   (32*128 floats = 1024 float4)
#pragma unroll
    for (int it = 0; it < 4; it++) {
        const int idx = it * 256 + t;          // float4 index
        const int a   = idx >> 5;
        const int c4  = (idx & 31) * 4;
        *(float4*)(xin + (size_t)(node0 + a) * 192 + c4) =
            *(const float4*)(srep + (size_t)(node0 + a) * 128 + c4);
    }
    // xin[:,128:192] = ||vV||  (32 nodes x 64 cols)
#pragma unroll
    for (int it = 0; it < 8; it++) {
        const int idx = it * 256 + t;
        const int a   = idx >> 6;
        const int c   = idx & 63;
        const float v0 = Cs[(3 * a + 0) * 128 + c];
        const float v1 = Cs[(3 * a + 1) * 128 + c];
        const float v2 = Cs[(3 * a + 2) * 128 + c];
        xin[(size_t)(node0 + a) * 192 + 128 + c] = sqrtf(v0 * v0 + v1 * v1 + v2 * v2);
    }
}

// ---------- gemmN: C = act(A@W + bias), 64-row x 64-col blocks --------------
// 256 threads, 4x4 micro-tile. Grid: (M/64, 128/64).
template<int ACT>
__global__ __launch_bounds__(256)
void gemmN_k(const float* __restrict__ A, const float* __restrict__ W,
             const float* __restrict__ bias, float* __restrict__ C,
             int M, int K) {
    __shared__ float As[8][64];
    __shared__ float Bs[8][64];
    const int t  = threadIdx.x;
    const int tx = t & 15;                     // cols tx*4..+3
    const int ty = t >> 4;                     // rows ty*4..+3
    const int row0 = blockIdx.x * 64;
    const int col0 = blockIdx.y * 64;

    float acc[4][4];
#pragma unroll
    for (int i = 0; i < 4; i++)
#pragma unroll
        for (int j = 0; j < 4; j++) acc[i][j] = 0.0f;

    for (int kc = 0; kc < K; kc += 8) {
        {
            const int m  = t >> 2;
            const int k2 = (t & 3) * 2;
            float2 av = *(const float2*)(A + (size_t)(row0 + m) * K + kc + k2);
            As[k2 + 0][m] = av.x; As[k2 + 1][m] = av.y;
        }
        {
            const int kb = t >> 5;
            const int n2 = (t & 31) * 2;
            *(float2*)&Bs[kb][n2] = *(const float2*)(W + (size_t)(kc + kb) * 128 + col0 + n2);
        }
        __syncthreads();
#pragma unroll
        for (int k = 0; k < 8; k++) {
            float af[4], bf[4];
            *(float4*)&af[0] = *(const float4*)&As[k][ty * 4];
            *(float4*)&bf[0] = *(const float4*)&Bs[k][tx * 4];
#pragma unroll
            for (int i = 0; i < 4; i++)
#pragma unroll
                for (int j = 0; j < 4; j++) acc[i][j] += af[i] * bf[j];
        }
        __syncthreads();
    }
#pragma unroll
    for (int i = 0; i < 4; i++) {
        const int row = row0 + ty * 4 + i;
        float v[4];
#pragma unroll
        for (int j = 0; j < 4; j++) {
            float x = acc[i][j] + bias[col0 + tx * 4 + j];
            if (ACT == 1) x = silu_f(x);
            v[j] = x;
        }
        *(float4*)(C + (size_t)row * 128 + col0 + tx * 4) = *(float4*)&v[0];
    }
}

// ---------------- glue2: per-node block-1 epilogue + full block-2 -----------
#define RED64(v) { v += __shfl_xor(v, 1); v += __shfl_xor(v, 2); v += __shfl_xor(v, 4); \
                   v += __shfl_xor(v, 8); v += __shfl_xor(v, 16); v += __shfl_xor(v, 32); }

__global__ __launch_bounds__(256)
void glue2_k(const float* __restrict__ x1, const float* __restrict__ vmix,
             const float* __restrict__ mixW2,
             const float* __restrict__ W1, const float* __restrict__ b1,
             const float* __restrict__ W2, const float* __restrict__ b2,
             float* __restrict__ l0v, float* __restrict__ l1v) {
    __shared__ float s1s[4][64];
    const int t = threadIdx.x;
    const int w = t >> 6, lane = t & 63;
    const int n = blockIdx.x * 4 + w;

    const float xa = x1[(size_t)n * 128 + lane];        // pre-silu s_out
    const float xb = x1[(size_t)n * 128 + 64 + lane];   // gate
    const float s1 = silu_f(xa);
    const float v1_0 = xb * vmix[((size_t)(3 * n + 0)) * 128 + 64 + lane];
    const float v1_1 = xb * vmix[((size_t)(3 * n + 1)) * 128 + 64 + lane];
    const float v1_2 = xb * vmix[((size_t)(3 * n + 2)) * 128 + 64 + lane];

    const float w0 = mixW2[lane * 2 + 0], w1 = mixW2[lane * 2 + 1];
    float p0 = v1_0 * w0, p1 = v1_0 * w1;
    float p2 = v1_1 * w0, p3 = v1_1 * w1;
    float p4 = v1_2 * w0, p5 = v1_2 * w1;
    RED64(p0); RED64(p1); RED64(p2); RED64(p3); RED64(p4); RED64(p5);
    const float vn2 = sqrtf(p0 * p0 + p2 * p2 + p4 * p4);

    s1s[w][lane] = s1;
    __syncthreads();

    float acc = b1[lane] + vn2 * W1[64 * 64 + lane];
#pragma unroll 8
    for (int i2 = 0; i2 < 64; i2++) acc += s1s[w][i2] * W1[i2 * 64 + lane];
    const float h2 = silu_f(acc);

    float q0 = h2 * W2[lane * 2 + 0];
    float q1 = h2 * W2[lane * 2 + 1];
    RED64(q0); RED64(q1);

    if (lane == 0) {
        const float s_out = q0 + b2[0];   // sact=False: no silu
        const float gate  = q1 + b2[1];
        l0v[n] = s_out;
        l1v[(size_t)n * 3 + 0] = gate * p1;
        l1v[(size_t)n * 3 + 1] = gate * p3;
        l1v[(size_t)n * 3 + 2] = gate * p5;
    }
}

// ---------- pairpre: per-node-j first-layer factorization tables ------------
// Pv[(a*30+h)*NN + j] = sum_b l1v[j,b] * vvW1[3a+b, h]
// Pr[(a*30+h)*NN + j] = sum_b pos[j,b] * vrW1[3a+b, h]
// Ps[h*NN + j]        = sb1[h] + l0v[j] * sW1[1,h]
__global__ __launch_bounds__(256)
void pairpre_k(const float* __restrict__ l1v, const float* __restrict__ pos,
               const float* __restrict__ l0v,
               const float* __restrict__ vvW1, const float* __restrict__ vrW1,
               const float* __restrict__ sW1, const float* __restrict__ sb1,
               float* __restrict__ Pv, float* __restrict__ Pr,
               float* __restrict__ Ps) {
    const int h = threadIdx.x;                 // 0..31 (active < 30)
    const int j = blockIdx.x * 8 + threadIdx.y;
    if (h >= 30) return;
    const float lj0 = l1v[j * 3 + 0], lj1 = l1v[j * 3 + 1], lj2 = l1v[j * 3 + 2];
    const float pj0 = pos[j * 3 + 0], pj1 = pos[j * 3 + 1], pj2 = pos[j * 3 + 2];
#pragma unroll
    for (int a = 0; a < 3; a++) {
        float v = lj0 * vvW1[(3 * a + 0) * 30 + h] + lj1 * vvW1[(3 * a + 1) * 30 + h]
                + lj2 * vvW1[(3 * a + 2) * 30 + h];
        float r = pj0 * vrW1[(3 * a + 0) * 30 + h] + pj1 * vrW1[(3 * a + 1) * 30 + h]
                + pj2 * vrW1[(3 * a + 2) * 30 + h];
        Pv[(size_t)(a * 30 + h) * NNODES + j] = v;
        Pr[(size_t)(a * 30 + h) * NNODES + j] = r;
    }
    Ps[(size_t)h * NNODES + j] = sb1[h] + l0v[j] * sW1[30 + h];
}

// ---------------- pair kernel: factorized MLPs, rolled h-loops --------------
__global__ __launch_bounds__(192)
void pair_k(const float* __restrict__ l0v, const float* __restrict__ l1v,
            const float* __restrict__ Pv, const float* __restrict__ Pr,
            const float* __restrict__ Ps,
            const float* __restrict__ vvb1, const float* __restrict__ vrb1,
            const float* __restrict__ sW1,
            const float* __restrict__ vvW2, const float* __restrict__ vrW2,
            const float* __restrict__ sW2,
            const float* __restrict__ vvb2, const float* __restrict__ vrb2,
            const float* __restrict__ sb2,
            const float* __restrict__ hW1,  const float* __restrict__ hb1,
            const float* __restrict__ hW2,  const float* __restrict__ hb2,
            float* __restrict__ out) {
    const int t = threadIdx.x;
    const int b = blockIdx.y;
    const int di = (t >= 96) ? 1 : 0;
    const int i = blockIdx.x * 2 + di;
    const int j = t - di * 96;
    const int ni = b * A_ATOMS + i;
    const int nj = b * A_ATOMS + j;

    const float li0 = l1v[ni * 3 + 0], li1 = l1v[ni * 3 + 1], li2 = l1v[ni * 3 + 2];
    const float s0i = l0v[ni];

    float t9[9];
#pragma unroll
    for (int l = 0; l < 9; l++) t9[l] = vvb2[l] + vrb2[l] + sb2[l];

    for (int h = 0; h < 30; h++) {
        float av = vvb1[h] + li0 * Pv[(size_t)h * NNODES + nj]
                           + li1 * Pv[(size_t)(30 + h) * NNODES + nj]
                           + li2 * Pv[(size_t)(60 + h) * NNODES + nj];
        float ar = vrb1[h] + li0 * Pr[(size_t)h * NNODES + nj]
                           + li1 * Pr[(size_t)(30 + h) * NNODES + nj]
                           + li2 * Pr[(size_t)(60 + h) * NNODES + nj];
        float as = Ps[(size_t)h * NNODES + nj] + s0i * sW1[h];
        av = silu_f(av); ar = silu_f(ar); as = silu_f(as);
#pragma unroll
        for (int l = 0; l < 9; l++)
            t9[l] += av * vvW2[h * 9 + l] + ar * vrW2[h * 9 + l] + as * sW2[h * 9 + l];
    }

    float o9[9];
#pragma unroll
    for (int l = 0; l < 9; l++) o9[l] = hb2[l];
    for (int h = 0; h < 30; h++) {
        float a = hb1[h];
#pragma unroll
        for (int m = 0; m < 9; m++) a += t9[m] * hW1[m * 30 + h];
        a = silu_f(a);
#pragma unroll
        for (int l = 0; l < 9; l++) o9[l] += a * hW2[h * 9 + l];
    }

    // out[((b*A+i)*3+k)*288 + j*3 + l] = o9[3k+l]
    const size_t rb = (size_t)(b * A_ATOMS + i);
#pragma unroll
    for (int k = 0; k < 3; k++) {
        const size_t off = (rb * 3 + k) * 288 + (size_t)j * 3;
        out[off + 0] = o9[3 * k + 0];
        out[off + 1] = o9[3 * k + 1];
        out[off + 2] = o9[3 * k + 2];
    }
}

extern "C" void kernel_launch(void* const* d_in, const int* in_sizes, int n_in,
                              void* d_out, int out_size, void* d_ws, size_t ws_size,
                              hipStream_t stream) {
    const float* pos   = (const float*)d_in[0];
    const float* srep  = (const float*)d_in[1];
    const float* vrep  = (const float*)d_in[2];
    const float* mixW1 = (const float*)d_in[3];
    const float* sc1W1 = (const float*)d_in[4];
    const float* sc1b1 = (const float*)d_in[5];
    const float* sc1W2 = (const float*)d_in[6];
    const float* sc1b2 = (const float*)d_in[7];
    const float* mixW2 = (const float*)d_in[8];
    const float* sc2W1 = (const float*)d_in[9];
    const float* sc2b1 = (const float*)d_in[10];
    const float* sc2W2 = (const float*)d_in[11];
    const float* sc2b2 = (const float*)d_in[12];
    const float* vvW1  = (const float*)d_in[13];
    const float* vvb1  = (const float*)d_in[14];
    const float* vvW2  = (const float*)d_in[15];
    const float* vvb2  = (const float*)d_in[16];
    const float* vrW1  = (const float*)d_in[17];
    const float* vrb1  = (const float*)d_in[18];
    const float* vrW2  = (const float*)d_in[19];
    const float* vrb2  = (const float*)d_in[20];
    const float* sW1   = (const float*)d_in[21];
    const float* sb1   = (const float*)d_in[22];
    const float* sW2   = (const float*)d_in[23];
    const float* sb2   = (const float*)d_in[24];
    const float* hW1   = (const float*)d_in[25];
    const float* hb1   = (const float*)d_in[26];
    const float* hW2   = (const float*)d_in[27];
    const float* hb2   = (const float*)d_in[28];

    float* ws   = (float*)d_ws;
    float* vmix = ws;                       // 36864*128 = 4,718,592
    float* xin  = vmix + 4718592;           // 12288*192 = 2,359,296
    float* hmid = xin  + 2359296;           // 12288*128 = 1,572,864
    float* x1   = hmid + 1572864;           // 12288*128 = 1,572,864
    float* l0v  = x1   + 1572864;           // 12288
    float* l1v  = l0v  + 12288;             // 36864
    // P-tables alias vmix/xin (dead after glue2_k): 2,580,480 floats needed
    float* Pv   = ws;                       // 90*12288 = 1,105,920
    float* Pr   = Pv + 1105920;             // 1,105,920
    float* Ps   = Pr + 1105920;             // 30*12288 = 368,640
    float* outf = (float*)d_out;

    // 1. vmix = vector_rep @ mix_W1, fused norm -> xin
    gemm96_k<<<NROWS3 / 96, 256, 0, stream>>>(vrep, mixW1, srep, vmix, xin);
    // 2. hmid = silu(xin @ sc1_W1 + b1)
    gemmN_k<1><<<dim3(NNODES / 64, 2), 256, 0, stream>>>(xin, sc1W1, sc1b1, hmid, NNODES, 192);
    // 3. x1 = hmid @ sc1_W2 + b2
    gemmN_k<0><<<dim3(NNODES / 64, 2), 256, 0, stream>>>(hmid, sc1W2, sc1b2, x1, NNODES, 128);
    // 4. per-node epilogue + block 2 -> l0, l1
    glue2_k<<<NNODES / 4, 256, 0, stream>>>(x1, vmix, mixW2, sc2W1, sc2b1, sc2W2, sc2b2,
                                            l0v, l1v);
    // 5. per-j factorization tables (vmix/xin dead now; aliasing safe)
    pairpre_k<<<NNODES / 8, dim3(32, 8), 0, stream>>>(l1v, pos, l0v, vvW1, vrW1,
                                                      sW1, sb1, Pv, Pr, Ps);
    // 6. pair stage
    pair_k<<<dim3(A_ATOMS / 2, BATCH), 192, 0, stream>>>(
        l0v, l1v, Pv, Pr, Ps,
        vvb1, vrb1, sW1,
        vvW2, vrW2, sW2,
        vvb2, vrb2, sb2,
        hW1, hb1, hW2, hb2,
        outf);
}